// Round 2
// baseline (7003.075 us; speedup 1.0000x reference)
//
#include <hip/hip_runtime.h>

#define N_NODES 200000
#define N_DIM   64
#define N_EDGES 6400000
#define NBK     3125            // fine buckets of 64 rows (200000/64)
#define NSB     125             // sort blocks
#define EPB     (N_EDGES/NSB)   // 51200 edges per sort block

// ---- P1: per-sort-block histogram over 3125 buckets (LDS atomics only) ----
__global__ __launch_bounds__(256) void k_hist(const int* __restrict__ rows,
                                              int* __restrict__ mat) {
    __shared__ int h[NBK];
    int t = threadIdx.x;
    for (int i = t; i < NBK; i += 256) h[i] = 0;
    __syncthreads();
    int start = blockIdx.x * EPB;
    for (int j = t; j < EPB; j += 256) {
        int r = rows[start + j];
        atomicAdd(&h[r >> 6], 1);
    }
    __syncthreads();
    int* m = mat + blockIdx.x * NBK;
    for (int i = t; i < NBK; i += 256) m[i] = h[i];
}

// ---- P2a: per-bucket totals (column sums of mat) ----
__global__ __launch_bounds__(256) void k_tot(const int* __restrict__ mat,
                                             int* __restrict__ tot) {
    int b = blockIdx.x * 256 + threadIdx.x;
    if (b >= NBK) return;
    int s = 0;
    for (int blk = 0; blk < NSB; ++blk) s += mat[blk * NBK + b];
    tot[b] = s;
}

// ---- P2b: exclusive scan of 3125 totals -> base[], base[NBK]=E ----
__global__ __launch_bounds__(256) void k_scanbase(const int* __restrict__ tot,
                                                  int* __restrict__ base) {
    __shared__ int sm[256];
    int t = threadIdx.x;
    const int C = 13;                       // 256*13 = 3328 >= 3125
    int c0 = t * C;
    int loc[C];
    int s = 0;
#pragma unroll
    for (int i = 0; i < C; ++i) {
        int b = c0 + i;
        loc[i] = (b < NBK) ? tot[b] : 0;
        s += loc[i];
    }
    sm[t] = s;
    __syncthreads();
    for (int off = 1; off < 256; off <<= 1) {
        int x = (t >= off) ? sm[t - off] : 0;
        __syncthreads();
        sm[t] += x;
        __syncthreads();
    }
    int run = (t == 0) ? 0 : sm[t - 1];
#pragma unroll
    for (int i = 0; i < C; ++i) {
        int b = c0 + i;
        if (b < NBK) base[b] = run;
        run += loc[i];
    }
    if (t == 255) base[NBK] = run;          // grand total = E
}

// ---- P2c: rebase mat[blk][b] to global write positions ----
__global__ __launch_bounds__(256) void k_rebase(int* __restrict__ mat,
                                                const int* __restrict__ base) {
    int b = blockIdx.x * 256 + threadIdx.x;
    if (b >= NBK) return;
    int run = base[b];
    for (int blk = 0; blk < NSB; ++blk) {
        int v = mat[blk * NBK + b];
        mat[blk * NBK + b] = run;
        run += v;
    }
}

// ---- P3: scatter edges into bucket-sorted slots (LDS cursors, no global atomics) ----
__global__ __launch_bounds__(256) void k_scatter(const int* __restrict__ rows,
                                                 const int* __restrict__ cols,
                                                 const float* __restrict__ vals,
                                                 const int* __restrict__ mat,
                                                 int2* __restrict__ slots) {
    __shared__ int cur[NBK];
    int t = threadIdx.x;
    const int* m = mat + blockIdx.x * NBK;
    for (int i = t; i < NBK; i += 256) cur[i] = m[i];
    __syncthreads();
    int start = blockIdx.x * EPB;
    for (int j = t; j < EPB; j += 256) {
        int e = start + j;
        int r = rows[e];
        int pos = atomicAdd(&cur[r >> 6], 1);
        slots[pos] = make_int2(((r & 63) << 18) | cols[e], __float_as_int(vals[e]));
    }
}

// ---- SpMM over buckets: block b accumulates its 64 rows in LDS ----
// MODE 0: h=A@x; y=h; out = emb + h
// MODE 1: h=A@x; y=h; out += h
// MODE 2: h=A@x;      out = (out + h) * 0.25
template <int MODE>
__global__ __launch_bounds__(256) void spmm(const int* __restrict__ base,
                                            const int2* __restrict__ slots,
                                            const float* __restrict__ x,
                                            float* __restrict__ y,
                                            const float* __restrict__ emb,
                                            float* __restrict__ out) {
    __shared__ float acc[64][68];           // pad 68: 16-B aligned rows, bank spread
    int t = threadIdx.x;
    float* af = &acc[0][0];
    for (int i = t; i < 64 * 68; i += 256) af[i] = 0.f;
    __syncthreads();

    int b  = blockIdx.x;
    int s0 = base[b], s1 = base[b + 1];
    int lane = t & 15, eg = t >> 4;         // 16 edge-groups x 16 lanes

    for (int j = s0 + eg; j < s1; j += 16) {
        int2 sv = slots[j];
        int col = sv.x & 0x3FFFF;
        int rl  = ((unsigned)sv.x) >> 18;   // row-in-bucket, 6 bits
        float v = __int_as_float(sv.y);
        const float4 xr = *reinterpret_cast<const float4*>(x + (col << 6) + (lane << 2));
        int d = lane << 2;
        atomicAdd(&acc[rl][d + 0], v * xr.x);
        atomicAdd(&acc[rl][d + 1], v * xr.y);
        atomicAdd(&acc[rl][d + 2], v * xr.z);
        atomicAdd(&acc[rl][d + 3], v * xr.w);
    }
    __syncthreads();

    // epilogue: 64 rows x 16 float4 = 1024 float4 slots, 4 per thread
    int rowbase = b << 6;
#pragma unroll
    for (int k = 0; k < 4; ++k) {
        int idx = t + (k << 8);
        int row = idx >> 4;                 // 0..63
        int f4  = idx & 15;                 // 0..15
        float4 h = *reinterpret_cast<const float4*>(&acc[row][f4 << 2]);
        int o = ((rowbase + row) << 6) + (f4 << 2);
        if (MODE == 0) {
            float4 e = *reinterpret_cast<const float4*>(emb + o);
            *reinterpret_cast<float4*>(y + o) = h;
            *reinterpret_cast<float4*>(out + o) =
                make_float4(e.x + h.x, e.y + h.y, e.z + h.z, e.w + h.w);
        } else if (MODE == 1) {
            float4 a = *reinterpret_cast<const float4*>(out + o);
            *reinterpret_cast<float4*>(y + o) = h;
            *reinterpret_cast<float4*>(out + o) =
                make_float4(a.x + h.x, a.y + h.y, a.z + h.z, a.w + h.w);
        } else {
            float4 a = *reinterpret_cast<const float4*>(out + o);
            *reinterpret_cast<float4*>(out + o) =
                make_float4((a.x + h.x) * 0.25f, (a.y + h.y) * 0.25f,
                            (a.z + h.z) * 0.25f, (a.w + h.w) * 0.25f);
        }
    }
}

// ---- launch ----
extern "C" void kernel_launch(void* const* d_in, const int* in_sizes, int n_in,
                              void* d_out, int out_size, void* d_ws, size_t ws_size,
                              hipStream_t stream) {
    const float* emb  = (const float*)d_in[0];
    const float* vals = (const float*)d_in[1];
    const int*   rows = (const int*)d_in[2];
    const int*   cols = (const int*)d_in[3];
    float*       out  = (float*)d_out;
    char*        ws   = (char*)d_ws;

    // workspace layout (16-B aligned offsets), total ~155.2 MB
    const size_t OFF_SLOTS = 0;                                  // 51,200,000
    const size_t OFF_MAT   = 51200000;                           // 1,562,500 -> pad 1,572,864
    const size_t OFF_TOT   = OFF_MAT + 1572864;                  // 12,500 -> pad 16,384
    const size_t OFF_BASE  = OFF_TOT + 16384;                    // 12,504 -> pad 16,384
    const size_t OFF_BUFA  = OFF_BASE + 16384;                   // 51,200,000
    const size_t OFF_BUFB  = OFF_BUFA + 51200000;                // 51,200,000

    int2*  slots = (int2*)(ws + OFF_SLOTS);
    int*   mat   = (int*)(ws + OFF_MAT);
    int*   tot   = (int*)(ws + OFF_TOT);
    int*   base  = (int*)(ws + OFF_BASE);
    float* bufA  = (float*)(ws + OFF_BUFA);
    float* bufB  = (float*)(ws + OFF_BUFB);

    k_hist    <<<NSB, 256, 0, stream>>>(rows, mat);
    k_tot     <<<13,  256, 0, stream>>>(mat, tot);
    k_scanbase<<<1,   256, 0, stream>>>(tot, base);
    k_rebase  <<<13,  256, 0, stream>>>(mat, base);
    k_scatter <<<NSB, 256, 0, stream>>>(rows, cols, vals, mat, slots);

    spmm<0><<<NBK, 256, 0, stream>>>(base, slots, emb,  bufA, emb, out);
    spmm<1><<<NBK, 256, 0, stream>>>(base, slots, bufA, bufB, nullptr, out);
    spmm<2><<<NBK, 256, 0, stream>>>(base, slots, bufB, nullptr, nullptr, out);
}

// Round 3
// 1131.659 us; speedup vs baseline: 6.1883x; 6.1883x over previous
//
#include <hip/hip_runtime.h>

#define N_NODES 200000
#define N_DIM   64
#define N_EDGES 6400000
#define NBK     3125            // buckets of 64 rows
#define NSB     250             // sort blocks
#define EPB     (N_EDGES/NSB)   // 25600 edges per sort block
#define ROWSORT_CAP 4096        // LDS-staged bucket cap (avg 2048, +45 sigma)

// ---- P1: per-sort-block histogram over 3125 buckets (LDS atomics only) ----
__global__ __launch_bounds__(256) void k_hist(const int* __restrict__ rows,
                                              int* __restrict__ mat) {
    __shared__ int h[NBK];
    int t = threadIdx.x;
    for (int i = t; i < NBK; i += 256) h[i] = 0;
    __syncthreads();
    int start = blockIdx.x * EPB;
    for (int j = t; j < EPB; j += 256) {
        int r = rows[start + j];
        atomicAdd(&h[r >> 6], 1);
    }
    __syncthreads();
    int* m = mat + blockIdx.x * NBK;
    for (int i = t; i < NBK; i += 256) m[i] = h[i];
}

// ---- P2a: per-bucket totals ----
__global__ __launch_bounds__(256) void k_tot(const int* __restrict__ mat,
                                             int* __restrict__ tot) {
    int b = blockIdx.x * 256 + threadIdx.x;
    if (b >= NBK) return;
    int s = 0;
    for (int blk = 0; blk < NSB; ++blk) s += mat[blk * NBK + b];
    tot[b] = s;
}

// ---- P2b: exclusive scan of 3125 totals -> base[], base[NBK]=E ----
__global__ __launch_bounds__(256) void k_scanbase(const int* __restrict__ tot,
                                                  int* __restrict__ base) {
    __shared__ int sm[256];
    int t = threadIdx.x;
    const int C = 13;                       // 256*13 = 3328 >= 3125
    int c0 = t * C;
    int loc[C];
    int s = 0;
#pragma unroll
    for (int i = 0; i < C; ++i) {
        int b = c0 + i;
        loc[i] = (b < NBK) ? tot[b] : 0;
        s += loc[i];
    }
    sm[t] = s;
    __syncthreads();
    for (int off = 1; off < 256; off <<= 1) {
        int x = (t >= off) ? sm[t - off] : 0;
        __syncthreads();
        sm[t] += x;
        __syncthreads();
    }
    int run = (t == 0) ? 0 : sm[t - 1];
#pragma unroll
    for (int i = 0; i < C; ++i) {
        int b = c0 + i;
        if (b < NBK) base[b] = run;
        run += loc[i];
    }
    if (t == 255) base[NBK] = run;          // = E
}

// ---- P2c: rebase mat[blk][b] to global write positions ----
__global__ __launch_bounds__(256) void k_rebase(int* __restrict__ mat,
                                                const int* __restrict__ base) {
    int b = blockIdx.x * 256 + threadIdx.x;
    if (b >= NBK) return;
    int run = base[b];
    for (int blk = 0; blk < NSB; ++blk) {
        int v = mat[blk * NBK + b];
        mat[blk * NBK + b] = run;
        run += v;
    }
}

// ---- P3: scatter edges into bucket-sorted slots (LDS cursors) ----
__global__ __launch_bounds__(256) void k_scatter(const int* __restrict__ rows,
                                                 const int* __restrict__ cols,
                                                 const float* __restrict__ vals,
                                                 const int* __restrict__ mat,
                                                 int2* __restrict__ slots) {
    __shared__ int cur[NBK];
    int t = threadIdx.x;
    const int* m = mat + blockIdx.x * NBK;
    for (int i = t; i < NBK; i += 256) cur[i] = m[i];
    __syncthreads();
    int start = blockIdx.x * EPB;
    for (int j = t; j < EPB; j += 256) {
        int e = start + j;
        int r = rows[e];
        int pos = atomicAdd(&cur[r >> 6], 1);
        slots[pos] = make_int2(((r & 63) << 18) | cols[e], __float_as_int(vals[e]));
    }
}

// ---- P4: in-bucket counting sort by row; emit per-row offsets ----
__global__ __launch_bounds__(256) void k_rowsort(const int* __restrict__ base,
                                                 int2* __restrict__ slots,
                                                 int2* __restrict__ spill,
                                                 int* __restrict__ offsets) {
    __shared__ int2 buf[ROWSORT_CAP];       // 32 KiB
    __shared__ int cnt[64], pos[64], cursor[64];
    int t = threadIdx.x, b = blockIdx.x;
    int s0 = base[b], s1 = base[b + 1], n = s1 - s0;
    if (t < 64) cnt[t] = 0;
    __syncthreads();
    bool lds = (n <= ROWSORT_CAP);
    if (lds) {
        for (int i = t; i < n; i += 256) {
            int2 v = slots[s0 + i];
            buf[i] = v;
            atomicAdd(&cnt[((unsigned)v.x) >> 18], 1);
        }
    } else {                                // statistically unreachable fallback
        for (int i = t; i < n; i += 256) {
            int2 v = slots[s0 + i];
            spill[s0 + i] = v;
            atomicAdd(&cnt[((unsigned)v.x) >> 18], 1);
        }
        __threadfence();
    }
    __syncthreads();
    if (t == 0) {
        int run = 0;
        for (int r = 0; r < 64; ++r) { int c = cnt[r]; pos[r] = run; cursor[r] = run; run += c; }
    }
    __syncthreads();
    if (t < 64) offsets[(b << 6) + t] = s0 + pos[t];
    if (t == 64 && b == NBK - 1) offsets[N_NODES] = s1;
    if (lds) {
        for (int i = t; i < n; i += 256) {
            int2 v = buf[i];
            int p = atomicAdd(&cursor[((unsigned)v.x) >> 18], 1);
            slots[s0 + p] = make_int2(v.x & 0x3FFFF, v.y);
        }
    } else {
        for (int i = t; i < n; i += 256) {
            int2 v = spill[s0 + i];
            int p = atomicAdd(&cursor[((unsigned)v.x) >> 18], 1);
            slots[s0 + p] = make_int2(v.x & 0x3FFFF, v.y);
        }
    }
}

// ---- SpMM: 16 lanes per row, register accumulate, 4-wide pipelined gathers ----
// MODE 0: h=A@x; y=h; out = emb + h
// MODE 1: h=A@x; y=h; out += h
// MODE 2: h=A@x;      out = (out + h) * 0.25
template <int MODE>
__global__ __launch_bounds__(256) void spmm(const int* __restrict__ offsets,
                                            const int2* __restrict__ slots,
                                            const float* __restrict__ x,
                                            float* __restrict__ y,
                                            const float* __restrict__ emb,
                                            float* __restrict__ out) {
    int t    = threadIdx.x;
    int r    = blockIdx.x * 16 + (t >> 4);
    int lane = t & 15;
    int j0 = offsets[r], j1 = offsets[r + 1];

    float4 acc = make_float4(0.f, 0.f, 0.f, 0.f);
    int j = j0;
    for (; j + 4 <= j1; j += 4) {
        int2 e0 = slots[j], e1 = slots[j + 1], e2 = slots[j + 2], e3 = slots[j + 3];
        const float4 x0 = *reinterpret_cast<const float4*>(x + (e0.x << 6) + (lane << 2));
        const float4 x1 = *reinterpret_cast<const float4*>(x + (e1.x << 6) + (lane << 2));
        const float4 x2 = *reinterpret_cast<const float4*>(x + (e2.x << 6) + (lane << 2));
        const float4 x3 = *reinterpret_cast<const float4*>(x + (e3.x << 6) + (lane << 2));
        float v0 = __int_as_float(e0.y), v1 = __int_as_float(e1.y);
        float v2 = __int_as_float(e2.y), v3 = __int_as_float(e3.y);
        acc.x = fmaf(v0, x0.x, acc.x); acc.y = fmaf(v0, x0.y, acc.y);
        acc.z = fmaf(v0, x0.z, acc.z); acc.w = fmaf(v0, x0.w, acc.w);
        acc.x = fmaf(v1, x1.x, acc.x); acc.y = fmaf(v1, x1.y, acc.y);
        acc.z = fmaf(v1, x1.z, acc.z); acc.w = fmaf(v1, x1.w, acc.w);
        acc.x = fmaf(v2, x2.x, acc.x); acc.y = fmaf(v2, x2.y, acc.y);
        acc.z = fmaf(v2, x2.z, acc.z); acc.w = fmaf(v2, x2.w, acc.w);
        acc.x = fmaf(v3, x3.x, acc.x); acc.y = fmaf(v3, x3.y, acc.y);
        acc.z = fmaf(v3, x3.z, acc.z); acc.w = fmaf(v3, x3.w, acc.w);
    }
    for (; j < j1; ++j) {
        int2 e = slots[j];
        const float4 xr = *reinterpret_cast<const float4*>(x + (e.x << 6) + (lane << 2));
        float v = __int_as_float(e.y);
        acc.x = fmaf(v, xr.x, acc.x); acc.y = fmaf(v, xr.y, acc.y);
        acc.z = fmaf(v, xr.z, acc.z); acc.w = fmaf(v, xr.w, acc.w);
    }

    int o = (r << 6) + (lane << 2);
    if (MODE == 0) {
        float4 e = *reinterpret_cast<const float4*>(emb + o);
        *reinterpret_cast<float4*>(y + o) = acc;
        *reinterpret_cast<float4*>(out + o) =
            make_float4(e.x + acc.x, e.y + acc.y, e.z + acc.z, e.w + acc.w);
    } else if (MODE == 1) {
        float4 a = *reinterpret_cast<const float4*>(out + o);
        *reinterpret_cast<float4*>(y + o) = acc;
        *reinterpret_cast<float4*>(out + o) =
            make_float4(a.x + acc.x, a.y + acc.y, a.z + acc.z, a.w + acc.w);
    } else {
        float4 a = *reinterpret_cast<const float4*>(out + o);
        *reinterpret_cast<float4*>(out + o) =
            make_float4((a.x + acc.x) * 0.25f, (a.y + acc.y) * 0.25f,
                        (a.z + acc.z) * 0.25f, (a.w + acc.w) * 0.25f);
    }
}

// ---- launch ----
extern "C" void kernel_launch(void* const* d_in, const int* in_sizes, int n_in,
                              void* d_out, int out_size, void* d_ws, size_t ws_size,
                              hipStream_t stream) {
    const float* emb  = (const float*)d_in[0];
    const float* vals = (const float*)d_in[1];
    const int*   rows = (const int*)d_in[2];
    const int*   cols = (const int*)d_in[3];
    float*       out  = (float*)d_out;
    char*        ws   = (char*)d_ws;

    // workspace layout (fits in 157.79 MB proven available in R1)
    const size_t OFF_SLOTS  = 0;                       // 51,200,000
    const size_t OFF_MAT    = 51200000;                // 250*3125*4 = 3,125,000
    const size_t OFF_TOT    = 54325248;                // 12,500
    const size_t OFF_BASE   = 54337792;                // 12,504
    const size_t OFF_ROWOFF = 54350336;                // 800,004
    const size_t OFF_BUFA   = 55150592;                // 51,200,000
    const size_t OFF_BUFB   = 106350592;               // 51,200,000 (also rowsort spill)

    int2*  slots  = (int2*)(ws + OFF_SLOTS);
    int*   mat    = (int*)(ws + OFF_MAT);
    int*   tot    = (int*)(ws + OFF_TOT);
    int*   base   = (int*)(ws + OFF_BASE);
    int*   rowoff = (int*)(ws + OFF_ROWOFF);
    float* bufA   = (float*)(ws + OFF_BUFA);
    float* bufB   = (float*)(ws + OFF_BUFB);

    k_hist    <<<NSB,  256, 0, stream>>>(rows, mat);
    k_tot     <<<13,   256, 0, stream>>>(mat, tot);
    k_scanbase<<<1,    256, 0, stream>>>(tot, base);
    k_rebase  <<<13,   256, 0, stream>>>(mat, base);
    k_scatter <<<NSB,  256, 0, stream>>>(rows, cols, vals, mat, slots);
    k_rowsort <<<NBK,  256, 0, stream>>>(base, slots, (int2*)bufB, rowoff);

    spmm<0><<<N_NODES / 16, 256, 0, stream>>>(rowoff, slots, emb,  bufA, emb, out);
    spmm<1><<<N_NODES / 16, 256, 0, stream>>>(rowoff, slots, bufA, bufB, nullptr, out);
    spmm<2><<<N_NODES / 16, 256, 0, stream>>>(rowoff, slots, bufB, nullptr, nullptr, out);
}